// Round 9
// baseline (226.511 us; speedup 1.0000x reference)
//
#include <hip/hip_runtime.h>

#define N_NODES 50000
#define N_EDGES 800000
#define IN_CH   128
#define HID     128
#define OUT_CH  64

#define NBUCK 196          // ceil(50000/256) dst buckets
#define BCAP  5120         // slack capacity per bucket (mean 4082, +16 sigma)
#define XPAD  136          // 128 bf16 + 8 pad

#define G1_BLOCKS ((N_NODES + 63) / 64)        // 782 gemm1 tiles
#define GSPLIT 391                             // gemm1 tiles in phase-0 launch

#define PLANE (N_NODES * 32)   // ushorts per 32-channel plane (3.2 MB, < 4MB L2/XCD)
#define NROWB 3125             // node-blocks per epoch (16 rows each)

typedef __attribute__((ext_vector_type(8))) short bf16x8;
typedef __attribute__((ext_vector_type(4))) float f32x4;
typedef unsigned short ushort_t;

__device__ __forceinline__ unsigned short f2bf(float f) {
    unsigned u = __float_as_uint(f);
    u += 0x7fffu + ((u >> 16) & 1u);      // RNE
    return (unsigned short)(u >> 16);
}
__device__ __forceinline__ unsigned pack2(float a, float b) {
    return (unsigned)f2bf(a) | ((unsigned)f2bf(b) << 16);
}
__device__ __forceinline__ float bf_lo(unsigned u) { return __uint_as_float(u << 16); }
__device__ __forceinline__ float bf_hi(unsigned u) { return __uint_as_float(u & 0xffff0000u); }

// ========= setup: zero bucket cursors + bf16-transpose weights =========

__global__ __launch_bounds__(256) void k_prep(const float* __restrict__ W1,
                                              const float* __restrict__ W2,
                                              ushort_t* __restrict__ W1t,
                                              ushort_t* __restrict__ W2t,
                                              int* __restrict__ bcur) {
    if (blockIdx.x == 0 && threadIdx.x < NBUCK) bcur[threadIdx.x] = 0;
    int i = blockIdx.x * 256 + threadIdx.x;
    if (i < 128 * 128) {
        int k = i >> 7, c = i & 127;
        W1t[c * 128 + k] = f2bf(W1[k * 128 + c]);
    } else {
        int j = i - 128 * 128;
        if (j < 128 * 64) {
            int k = j >> 6, c = j & 63;
            W2t[c * 128 + k] = f2bf(W2[k * 64 + c]);
        }
    }
}

// ========= fused stage kernel (R7 structure — gemm1 rides free) =========
// phase 0: blocks [0,NBUCK) = LDS-binned scatter -> rec ; rest = gemm1 [0,GSPLIT)
// phase 1: blocks [0,NBUCK) = LDS-grouped CSR    -> col ; rest = gemm1 [GSPLIT,782)
// gemm1 writes g1 in PLANAR layout: 4 planes of 32 channels, 3.2MB each, so the
// aggregation epochs can hold one plane fully in every XCD's 4MB L2.

__global__ __launch_bounds__(256) void k_stage(const int phase, const int tile0,
                                               const int* __restrict__ src,
                                               const int* __restrict__ dst,
                                               int* __restrict__ bcur,
                                               unsigned* __restrict__ rec,
                                               const float* __restrict__ x,
                                               const ushort_t* __restrict__ W1t,
                                               ushort_t* __restrict__ g1q,
                                               int* __restrict__ row_beg,
                                               int* __restrict__ row_end,
                                               float* __restrict__ dis,
                                               int* __restrict__ col) {
    __shared__ char smem[52224];
    const int tid = threadIdx.x;

    if (blockIdx.x < NBUCK) {
        if (phase == 0) {
            // ---- LDS-binned scatter: 4096 edges -> bucket-grouped rec runs ----
            int* cnt  = (int*)smem;
            int* boff = cnt + 256;
            int* gdel = boff + 256;
            int* bid  = gdel + 256;
            unsigned* stage = (unsigned*)(bid + 4096);

            const int base = blockIdx.x * 4096;
            const int nval = min(4096, N_EDGES - base);

            int dreg[16];
#pragma unroll
            for (int k = 0; k < 16; ++k) {
                int e = base + k * 256 + tid;
                dreg[k] = (e < N_EDGES) ? dst[e] : -1;
            }
            cnt[tid] = 0;
            __syncthreads();
#pragma unroll
            for (int k = 0; k < 16; ++k)
                if (dreg[k] >= 0) atomicAdd(&cnt[dreg[k] >> 8], 1);
            __syncthreads();
            int* s = bid;
            int c = cnt[tid];
            s[tid] = c;
            __syncthreads();
            for (int off = 1; off < 256; off <<= 1) {
                int u = (tid >= off) ? s[tid - off] : 0;
                __syncthreads();
                s[tid] += u;
                __syncthreads();
            }
            boff[tid] = s[tid] - c;
            if (tid < NBUCK && c > 0)
                gdel[tid] = tid * BCAP + atomicAdd(&bcur[tid], c) - boff[tid];
            __syncthreads();
            cnt[tid] = 0;
            __syncthreads();
#pragma unroll
            for (int k = 0; k < 16; ++k) {
                int e = base + k * 256 + tid;
                if (dreg[k] >= 0) {
                    int b = dreg[k] >> 8;
                    int rk = atomicAdd(&cnt[b], 1);
                    int p = boff[b] + rk;
                    stage[p] = (unsigned)src[e] | ((unsigned)(dreg[k] & 255) << 16);
                    bid[p] = b;
                }
            }
            __syncthreads();
            for (int i = tid; i < nval; i += 256) {
                int b = bid[i];
                int p = i + gdel[b];
                if (p < (b + 1) * BCAP)
                    rec[p] = stage[i];
            }
        } else {
            // ---- LDS-grouped CSR: bucket run -> row ptrs + dis + col ----
            int* hist = (int*)smem;
            int* sbuf = hist + 256;
            int* cur  = sbuf + 256;
            unsigned* stage = (unsigned*)(cur + 256);
            const int b = blockIdx.x;
            const int lo = b * BCAP;
            const int cnt = min(bcur[b], BCAP);

            hist[tid] = 0;
            __syncthreads();
            for (int j = tid; j < cnt; j += 256)
                atomicAdd(&hist[rec[lo + j] >> 16], 1);
            __syncthreads();
            int deg = hist[tid];
            sbuf[tid] = deg;
            __syncthreads();
            for (int off = 1; off < 256; off <<= 1) {
                int u = (tid >= off) ? sbuf[tid - off] : 0;
                __syncthreads();
                sbuf[tid] += u;
                __syncthreads();
            }
            int lbeg = sbuf[tid] - deg;
            int node = (b << 8) + tid;
            if (node < N_NODES) {
                row_beg[node] = lo + lbeg;
                row_end[node] = lo + lbeg + deg;
                dis[node] = rsqrtf((float)deg + 1.0f);
            }
            cur[tid] = lbeg;
            __syncthreads();
            for (int j = tid; j < cnt; j += 256) {
                unsigned r = rec[lo + j];
                int rk = atomicAdd(&cur[r >> 16], 1);
                stage[rk] = r & 0xffffu;
            }
            __syncthreads();
            for (int i = tid; i < cnt; i += 256)
                col[lo + i] = (int)stage[i];
        }
    } else {
        // ---- MFMA GEMM1 tile: g1 UNSCALED (x@W1), PLANAR write ----
        ushort_t* xs = (ushort_t*)smem;
        ushort_t* ws = (ushort_t*)(smem + 17408);
        const int bid = tile0 + (blockIdx.x - NBUCK);
        const int row0 = bid * 64;

        for (int i = tid; i < 64 * 32; i += 256) {
            int r = i >> 5, k4 = (i & 31) << 2;
            int gr = row0 + r;
            float4 v = make_float4(0.f, 0.f, 0.f, 0.f);
            if (gr < N_NODES) v = *(const float4*)&x[(long)gr * IN_CH + k4];
            ushort4 u;
            u.x = f2bf(v.x); u.y = f2bf(v.y); u.z = f2bf(v.z); u.w = f2bf(v.w);
            *(ushort4*)&xs[r * XPAD + k4] = u;
        }
        for (int i = tid; i < 128 * 16; i += 256) {
            int c = i >> 4, seg = i & 15;
            *(uint4*)&ws[c * XPAD + seg * 8] = *(const uint4*)&W1t[c * 128 + seg * 8];
        }
        __syncthreads();

        const int w = tid >> 6, lane = tid & 63;
        const int m = lane & 15, q = lane >> 4;
        const ushort_t* arow = &xs[(w * 16 + m) * XPAD + q * 8];
        const ushort_t* brow = &ws[m * XPAD + q * 8];

        f32x4 acc[8] = {};
#pragma unroll
        for (int k0 = 0; k0 < 128; k0 += 32) {
            bf16x8 a = *(const bf16x8*)(arow + k0);
#pragma unroll
            for (int nt = 0; nt < 8; ++nt) {
                bf16x8 b = *(const bf16x8*)(brow + nt * 16 * XPAD + k0);
                acc[nt] = __builtin_amdgcn_mfma_f32_16x16x32_bf16(a, b, acc[nt], 0, 0, 0);
            }
        }

#pragma unroll
        for (int reg = 0; reg < 4; ++reg) {
            int gr = row0 + w * 16 + q * 4 + reg;
            if (gr < N_NODES) {
#pragma unroll
                for (int nt = 0; nt < 8; ++nt)    // plane nt>>1, in-plane ch (nt&1)*16+m
                    g1q[(long)(nt >> 1) * PLANE + gr * 32 + (nt & 1) * 16 + m]
                        = f2bf(acc[nt][reg]);
            }
        }
    }
}

// ===== layer-1 aggregate, channel-planar epochs =====
// Epoch qq = blockIdx/3125 (dispatch monotone in blockIdx -> at any instant all
// XCDs gather from the SAME 3.2MB plane, which is fully L2-resident everywhere).
// 64B gather granule; 16 edge slots/wave; plain R7 numerics (dis[s] per row).

__global__ __launch_bounds__(256) void k_agg1(const int* __restrict__ row_beg,
                                              const int* __restrict__ row_end,
                                              const int* __restrict__ col,
                                              const float* __restrict__ dis,
                                              const ushort_t* __restrict__ g1q,
                                              const float* __restrict__ b1,
                                              ushort_t* __restrict__ a1q) {
    const int qq = blockIdx.x / NROWB;       // channel-quarter epoch 0..3
    const int nb = blockIdx.x % NROWB;
    const int tid = threadIdx.x;
    const int w = tid >> 6, lane = tid & 63;
    const int es = lane >> 2;                // edge slot 0..15
    const int seg = lane & 3;                // 16B segment within 64B row-quarter
    const uint4* G = (const uint4*)(g1q + (long)qq * PLANE);
    const int r0 = nb * 16;

    for (int rr = 0; rr < 4; ++rr) {
        const int r = r0 + w * 4 + rr;
        const int beg = row_beg[r], end = row_end[r];

        float acc[8] = {};
        for (int e = beg + es; e < end; e += 16) {
            int s = col[e];
            float d = dis[s];
            uint4 u = G[s * 4 + seg];
            acc[0] += bf_lo(u.x) * d; acc[1] += bf_hi(u.x) * d;
            acc[2] += bf_lo(u.y) * d; acc[3] += bf_hi(u.y) * d;
            acc[4] += bf_lo(u.z) * d; acc[5] += bf_hi(u.z) * d;
            acc[6] += bf_lo(u.w) * d; acc[7] += bf_hi(u.w) * d;
        }
#pragma unroll
        for (int off = 4; off < 64; off <<= 1)
#pragma unroll
            for (int j = 0; j < 8; ++j) acc[j] += __shfl_xor(acc[j], off);

        if (es == 0) {
            const float d = dis[r];
            uint4 u = G[r * 4 + seg];          // self-loop (scaled by dis[r])
            acc[0] += bf_lo(u.x) * d; acc[1] += bf_hi(u.x) * d;
            acc[2] += bf_lo(u.y) * d; acc[3] += bf_hi(u.y) * d;
            acc[4] += bf_lo(u.z) * d; acc[5] += bf_hi(u.z) * d;
            acc[6] += bf_lo(u.w) * d; acc[7] += bf_hi(u.w) * d;
            float o[8];
#pragma unroll
            for (int j = 0; j < 8; ++j)
                o[j] = fmaxf(acc[j] * d + b1[qq * 32 + seg * 8 + j], 0.f);
            uint4 pw;
            pw.x = pack2(o[0], o[1]); pw.y = pack2(o[2], o[3]);
            pw.z = pack2(o[4], o[5]); pw.w = pack2(o[6], o[7]);
            *(uint4*)&a1q[(long)qq * PLANE + r * 32 + seg * 8] = pw;
        }
    }
}

// ====== MFMA GEMM2: g3 = bf16((a1 @ W2) * dis[row]); planar in & out ======

__global__ __launch_bounds__(256) void k_gemm2(const ushort_t* __restrict__ a1q,
                                               const ushort_t* __restrict__ W2t,
                                               const float* __restrict__ dis,
                                               ushort_t* __restrict__ g3h) {
    __shared__ ushort_t xs[64 * XPAD];
    __shared__ ushort_t ws[64 * XPAD];
    const int tid = threadIdx.x;
    const int row0 = blockIdx.x * 64;

    for (int i = tid; i < 64 * 16; i += 256) {
        int r = i >> 4, seg = i & 15;
        int gr = row0 + r;
        uint4 v = make_uint4(0u, 0u, 0u, 0u);
        if (gr < N_NODES)
            v = *(const uint4*)&a1q[(long)(seg >> 2) * PLANE + gr * 32 + (seg & 3) * 8];
        *(uint4*)&xs[r * XPAD + seg * 8] = v;
    }
    for (int i = tid; i < 64 * 16; i += 256) {
        int c = i >> 4, seg = i & 15;
        *(uint4*)&ws[c * XPAD + seg * 8] = *(const uint4*)&W2t[c * 128 + seg * 8];
    }
    __syncthreads();

    const int w = tid >> 6, lane = tid & 63;
    const int m = lane & 15, q = lane >> 4;
    const ushort_t* arow = &xs[(w * 16 + m) * XPAD + q * 8];
    const ushort_t* brow = &ws[m * XPAD + q * 8];

    f32x4 acc[4] = {};
#pragma unroll
    for (int k0 = 0; k0 < 128; k0 += 32) {
        bf16x8 a = *(const bf16x8*)(arow + k0);
#pragma unroll
        for (int nt = 0; nt < 4; ++nt) {
            bf16x8 b = *(const bf16x8*)(brow + nt * 16 * XPAD + k0);
            acc[nt] = __builtin_amdgcn_mfma_f32_16x16x32_bf16(a, b, acc[nt], 0, 0, 0);
        }
    }

#pragma unroll
    for (int reg = 0; reg < 4; ++reg) {
        int gr = row0 + w * 16 + q * 4 + reg;
        if (gr < N_NODES) {
            float d = dis[gr];
#pragma unroll
            for (int nt = 0; nt < 4; ++nt)    // plane nt>>1, in-plane ch (nt&1)*16+m
                g3h[(long)(nt >> 1) * PLANE + gr * 32 + (nt & 1) * 16 + m]
                    = f2bf(acc[nt][reg] * d);
        }
    }
}

// ===== layer-2 aggregate, channel-planar epochs (2 halves of 3.2MB) =====
// g3 pre-scaled by dis[src] -> plain sum; epoch hh = blockIdx/3125.

__global__ __launch_bounds__(256) void k_agg2(const int* __restrict__ row_beg,
                                              const int* __restrict__ row_end,
                                              const int* __restrict__ col,
                                              const float* __restrict__ dis,
                                              const ushort_t* __restrict__ g3h,
                                              const float* __restrict__ b2,
                                              float* __restrict__ out) {
    const int hh = blockIdx.x / NROWB;       // channel-half epoch 0..1
    const int nb = blockIdx.x % NROWB;
    const int tid = threadIdx.x;
    const int w = tid >> 6, lane = tid & 63;
    const int es = lane >> 2;
    const int seg = lane & 3;
    const uint4* G = (const uint4*)(g3h + (long)hh * PLANE);
    const int r0 = nb * 16;

    for (int rr = 0; rr < 4; ++rr) {
        const int r = r0 + w * 4 + rr;
        const int beg = row_beg[r], end = row_end[r];

        float acc[8] = {};
        for (int e = beg + es; e < end; e += 16) {
            int s = col[e];
            uint4 u = G[s * 4 + seg];
            acc[0] += bf_lo(u.x); acc[1] += bf_hi(u.x);
            acc[2] += bf_lo(u.y); acc[3] += bf_hi(u.y);
            acc[4] += bf_lo(u.z); acc[5] += bf_hi(u.z);
            acc[6] += bf_lo(u.w); acc[7] += bf_hi(u.w);
        }
#pragma unroll
        for (int off = 4; off < 64; off <<= 1)
#pragma unroll
            for (int j = 0; j < 8; ++j) acc[j] += __shfl_xor(acc[j], off);

        if (es == 0) {
            uint4 u = G[r * 4 + seg];          // self row (pre-scaled)
            acc[0] += bf_lo(u.x); acc[1] += bf_hi(u.x);
            acc[2] += bf_lo(u.y); acc[3] += bf_hi(u.y);
            acc[4] += bf_lo(u.z); acc[5] += bf_hi(u.z);
            acc[6] += bf_lo(u.w); acc[7] += bf_hi(u.w);
            const float d = dis[r];
            float4 o0, o1;
            const int cb = hh * 32 + seg * 8;
            o0.x = acc[0] * d + b2[cb + 0];
            o0.y = acc[1] * d + b2[cb + 1];
            o0.z = acc[2] * d + b2[cb + 2];
            o0.w = acc[3] * d + b2[cb + 3];
            o1.x = acc[4] * d + b2[cb + 4];
            o1.y = acc[5] * d + b2[cb + 5];
            o1.z = acc[6] * d + b2[cb + 6];
            o1.w = acc[7] * d + b2[cb + 7];
            *(float4*)&out[(long)r * OUT_CH + cb] = o0;
            *(float4*)&out[(long)r * OUT_CH + cb + 4] = o1;
        }
    }
}

// ================= launch =================

extern "C" void kernel_launch(void* const* d_in, const int* in_sizes, int n_in,
                              void* d_out, int out_size, void* d_ws, size_t ws_size,
                              hipStream_t stream) {
    const float* x   = (const float*)d_in[0];
    const int*   ei  = (const int*)d_in[1];
    const float* W1  = (const float*)d_in[2];
    const float* b1  = (const float*)d_in[3];
    const float* W2  = (const float*)d_in[4];
    const float* b2  = (const float*)d_in[5];
    float* out = (float*)d_out;

    const int* src = ei;
    const int* dst = ei + N_EDGES;

    char* p = (char*)d_ws;
    unsigned* rec = (unsigned*)p;         p += (long)NBUCK * BCAP * 4;   // 4.0 MB slack
    int* col     = (int*)p;               p += (long)NBUCK * BCAP * 4;   // 4.0 MB slack
    int* row_beg = (int*)p;               p += 50048 * 4;
    int* row_end = (int*)p;               p += 50048 * 4;
    int* bcur    = (int*)p;               p += 256 * 4;
    float* dis   = (float*)p;             p += 50048 * 4;
    ushort_t* W1t = (ushort_t*)p;         p += 128 * 128 * 2;
    ushort_t* W2t = (ushort_t*)p;         p += 128 * 64 * 2;
    ushort_t* g1q = (ushort_t*)p;         p += (long)4 * PLANE * 2;      // 12.8 MB planar
    ushort_t* a1q = (ushort_t*)p;         p += (long)4 * PLANE * 2;      // 12.8 MB planar
    ushort_t* g3h = (ushort_t*)p;                                         // 6.4 MB planar

    const int B = 256;

    k_prep<<<96, B, 0, stream>>>(W1, W2, W1t, W2t, bcur);
    // phase 0: LDS-binned scatter || first half of gemm1 (planar g1 write)
    k_stage<<<NBUCK + GSPLIT, B, 0, stream>>>(0, 0, src, dst, bcur, rec,
                                              x, W1t, g1q, row_beg, row_end, dis, col);
    // phase 1: LDS-grouped CSR || second half of gemm1
    k_stage<<<NBUCK + (G1_BLOCKS - GSPLIT), B, 0, stream>>>(1, GSPLIT, src, dst, bcur, rec,
                                              x, W1t, g1q, row_beg, row_end, dis, col);
    // agg1: 4 channel-quarter epochs, 3.2MB plane each (L2-resident per epoch)
    k_agg1<<<4 * NROWB, B, 0, stream>>>(row_beg, row_end, col, dis, g1q, b1, a1q);
    // gemm2: a1 @ W2 -> g3 planes (pre-scaled by dis[row])
    k_gemm2<<<(N_NODES + 63) / 64, B, 0, stream>>>(a1q, W2t, dis, g3h);
    // agg2: 2 channel-half epochs
    k_agg2<<<2 * NROWB, B, 0, stream>>>(row_beg, row_end, col, dis, g3h, b2, out);
}

// Round 10
// 172.924 us; speedup vs baseline: 1.3099x; 1.3099x over previous
//
#include <hip/hip_runtime.h>

#define N_NODES 50000
#define N_EDGES 800000
#define IN_CH   128
#define HID     128
#define OUT_CH  64

#define NBUCK 196          // ceil(50000/256) dst buckets
#define BCAP  5120         // slack capacity per bucket (mean 4082, +16 sigma)
#define XPAD  136          // 128 bf16 + 8 pad

typedef __attribute__((ext_vector_type(8))) short bf16x8;
typedef __attribute__((ext_vector_type(4))) float f32x4;
typedef unsigned short ushort_t;

__device__ __forceinline__ unsigned short f2bf(float f) {
    unsigned u = __float_as_uint(f);
    u += 0x7fffu + ((u >> 16) & 1u);      // RNE
    return (unsigned short)(u >> 16);
}
__device__ __forceinline__ unsigned pack2(float a, float b) {
    return (unsigned)f2bf(a) | ((unsigned)f2bf(b) << 16);
}
__device__ __forceinline__ float bf_lo(unsigned u) { return __uint_as_float(u << 16); }
__device__ __forceinline__ float bf_hi(unsigned u) { return __uint_as_float(u & 0xffff0000u); }

// ========= setup: zero bucket cursors + bf16-transpose weights =========

__global__ __launch_bounds__(256) void k_prep(const float* __restrict__ W1,
                                              const float* __restrict__ W2,
                                              ushort_t* __restrict__ W1t,
                                              ushort_t* __restrict__ W2t,
                                              int* __restrict__ bcur) {
    if (blockIdx.x == 0 && threadIdx.x < NBUCK) bcur[threadIdx.x] = 0;
    int i = blockIdx.x * 256 + threadIdx.x;
    if (i < 128 * 128) {
        int k = i >> 7, c = i & 127;
        W1t[c * 128 + k] = f2bf(W1[k * 128 + c]);
    } else {
        int j = i - 128 * 128;
        if (j < 128 * 64) {
            int k = j >> 6, c = j & 63;
            W2t[c * 128 + k] = f2bf(W2[k * 64 + c]);
        }
    }
}

// ========= MFMA GEMM1 standalone: g1 = bf16(x @ W1), UNSCALED =========

__global__ __launch_bounds__(256) void k_g1(const float* __restrict__ x,
                                            const ushort_t* __restrict__ W1t,
                                            ushort_t* __restrict__ g1) {
    __shared__ ushort_t xs[64 * XPAD];
    __shared__ ushort_t ws[128 * XPAD];
    const int tid = threadIdx.x;
    const int row0 = blockIdx.x * 64;

    for (int i = tid; i < 64 * 32; i += 256) {
        int r = i >> 5, k4 = (i & 31) << 2;
        int gr = row0 + r;
        float4 v = make_float4(0.f, 0.f, 0.f, 0.f);
        if (gr < N_NODES) v = *(const float4*)&x[(long)gr * IN_CH + k4];
        ushort4 u;
        u.x = f2bf(v.x); u.y = f2bf(v.y); u.z = f2bf(v.z); u.w = f2bf(v.w);
        *(ushort4*)&xs[r * XPAD + k4] = u;
    }
    for (int i = tid; i < 128 * 16; i += 256) {
        int c = i >> 4, seg = i & 15;
        *(uint4*)&ws[c * XPAD + seg * 8] = *(const uint4*)&W1t[c * 128 + seg * 8];
    }
    __syncthreads();

    const int w = tid >> 6, lane = tid & 63;
    const int m = lane & 15, q = lane >> 4;
    const ushort_t* arow = &xs[(w * 16 + m) * XPAD + q * 8];
    const ushort_t* brow = &ws[m * XPAD + q * 8];

    f32x4 acc[8] = {};
#pragma unroll
    for (int k0 = 0; k0 < 128; k0 += 32) {
        bf16x8 a = *(const bf16x8*)(arow + k0);
#pragma unroll
        for (int nt = 0; nt < 8; ++nt) {
            bf16x8 b = *(const bf16x8*)(brow + nt * 16 * XPAD + k0);
            acc[nt] = __builtin_amdgcn_mfma_f32_16x16x32_bf16(a, b, acc[nt], 0, 0, 0);
        }
    }

#pragma unroll
    for (int reg = 0; reg < 4; ++reg) {
        int gr = row0 + w * 16 + q * 4 + reg;
        if (gr < N_NODES) {
#pragma unroll
            for (int nt = 0; nt < 8; ++nt)
                g1[(long)gr * HID + nt * 16 + m] = f2bf(acc[nt][reg]);
        }
    }
}

// ========= LDS-binned scatter, 1024 threads (16 waves deep) =========
// The stage passes are latency-chain bound at 4 waves/CU (all counters ~0 in
// R5-R8). 1024 threads/block quarters the dependent round count (16->4 hist,
// 16->4 place) and gives 4x the waves to overlap each global/LDS latency.

__global__ __launch_bounds__(1024) void k_sc(const int* __restrict__ src,
                                             const int* __restrict__ dst,
                                             int* __restrict__ bcur,
                                             unsigned* __restrict__ rec) {
    __shared__ int cnt[256];
    __shared__ int boff[256];
    __shared__ int gdel[256];
    __shared__ int bid[4096];
    __shared__ unsigned stage[4096];
    const int tid = threadIdx.x;
    const int base = blockIdx.x * 4096;
    const int nval = min(4096, N_EDGES - base);

    int dreg[4];
#pragma unroll
    for (int k = 0; k < 4; ++k) {
        int e = base + k * 1024 + tid;
        dreg[k] = (e < N_EDGES) ? dst[e] : -1;
    }
    if (tid < 256) cnt[tid] = 0;
    __syncthreads();
#pragma unroll
    for (int k = 0; k < 4; ++k)
        if (dreg[k] >= 0) atomicAdd(&cnt[dreg[k] >> 8], 1);
    __syncthreads();
    int c = 0;
    if (tid < 256) { c = cnt[tid]; bid[tid] = c; }   // bid[0..255] = scan temp
    __syncthreads();
    for (int off = 1; off < 256; off <<= 1) {
        int u = 0;
        if (tid < 256 && tid >= off) u = bid[tid - off];
        __syncthreads();
        if (tid < 256) bid[tid] += u;
        __syncthreads();
    }
    if (tid < 256) {
        boff[tid] = bid[tid] - c;
        gdel[tid] = 0;
        if (tid < NBUCK && c > 0)
            gdel[tid] = tid * BCAP + atomicAdd(&bcur[tid], c) - boff[tid];
        cnt[tid] = 0;
    }
    __syncthreads();
#pragma unroll
    for (int k = 0; k < 4; ++k) {
        int e = base + k * 1024 + tid;
        if (dreg[k] >= 0) {
            int b = dreg[k] >> 8;
            int rk = atomicAdd(&cnt[b], 1);
            int p = boff[b] + rk;
            stage[p] = (unsigned)src[e] | ((unsigned)(dreg[k] & 255) << 16);
            bid[p] = b;
        }
    }
    __syncthreads();
    // dense sequential write-out: consecutive i -> consecutive global pos
    for (int i = tid; i < nval; i += 1024) {
        int b = bid[i];
        int p = i + gdel[b];
        if (p < (b + 1) * BCAP)               // overflow guard (never hits)
            rec[p] = stage[i];
    }
}

// ========= per-bucket CSR, 1024 threads (16 waves deep) =========

__global__ __launch_bounds__(1024) void k_csr(const int* __restrict__ bcur,
                                              const unsigned* __restrict__ rec,
                                              int* __restrict__ row_beg,
                                              int* __restrict__ row_end,
                                              float* __restrict__ dis,
                                              int* __restrict__ col) {
    __shared__ int hist[256];
    __shared__ int sbuf[256];
    __shared__ int cur[256];
    __shared__ unsigned stage[BCAP];
    const int tid = threadIdx.x;
    const int b = blockIdx.x;
    const int lo = b * BCAP;
    const int cnt = min(bcur[b], BCAP);

    if (tid < 256) hist[tid] = 0;
    __syncthreads();
    for (int j = tid; j < cnt; j += 1024)
        atomicAdd(&hist[rec[lo + j] >> 16], 1);
    __syncthreads();
    if (tid < 256) sbuf[tid] = hist[tid];
    __syncthreads();
    for (int off = 1; off < 256; off <<= 1) {
        int u = 0;
        if (tid < 256 && tid >= off) u = sbuf[tid - off];
        __syncthreads();
        if (tid < 256) sbuf[tid] += u;
        __syncthreads();
    }
    if (tid < 256) {
        int deg = hist[tid];
        int lbeg = sbuf[tid] - deg;
        int node = (b << 8) + tid;
        if (node < N_NODES) {
            row_beg[node] = lo + lbeg;
            row_end[node] = lo + lbeg + deg;
            dis[node] = rsqrtf((float)deg + 1.0f);
        }
        cur[tid] = lbeg;
    }
    __syncthreads();
    for (int j = tid; j < cnt; j += 1024) {
        unsigned r = rec[lo + j];
        int rk = atomicAdd(&cur[r >> 16], 1);
        stage[rk] = r & 0xffffu;
    }
    __syncthreads();
    for (int i = tid; i < cnt; i += 1024)
        col[lo + i] = (int)stage[i];
}

// ===== FUSED layer-1 aggregate + GEMM2 (R2 form — best measured: 46.0us) =====

__global__ __launch_bounds__(256) void k_agg1g2(const int* __restrict__ row_beg,
                                                const int* __restrict__ row_end,
                                                const int* __restrict__ col,
                                                const float* __restrict__ dis,
                                                const ushort_t* __restrict__ g1,
                                                const float* __restrict__ b1,
                                                const ushort_t* __restrict__ W2t,
                                                ushort_t* __restrict__ g3) {
    __shared__ ushort_t hs[16 * XPAD];
    const int tid = threadIdx.x;
    const int w = tid >> 6, lane = tid & 63;
    const int q = lane >> 4;            // edge slot 0..3
    const int seg = lane & 15;          // 16B segment
    const int cl = seg << 3;
    const uint4* G = (const uint4*)g1;
    const int r0 = blockIdx.x * 16;     // 50000 = 3125*16, no tail

    // ---- Phase A: aggregate 4 rows per wave ----
    for (int rr = 0; rr < 4; ++rr) {
        const int r = r0 + w * 4 + rr;
        const int beg = row_beg[r], end = row_end[r];

        float acc[8] = {};
        int e = beg + q;
        for (; e + 4 < end; e += 8) {
            int s0 = col[e], s1 = col[e + 4];
            float d0 = dis[s0], d1 = dis[s1];
            uint4 u0 = G[(long)s0 * 16 + seg];
            uint4 u1 = G[(long)s1 * 16 + seg];
            acc[0] += bf_lo(u0.x) * d0; acc[1] += bf_hi(u0.x) * d0;
            acc[2] += bf_lo(u0.y) * d0; acc[3] += bf_hi(u0.y) * d0;
            acc[4] += bf_lo(u0.z) * d0; acc[5] += bf_hi(u0.z) * d0;
            acc[6] += bf_lo(u0.w) * d0; acc[7] += bf_hi(u0.w) * d0;
            acc[0] += bf_lo(u1.x) * d1; acc[1] += bf_hi(u1.x) * d1;
            acc[2] += bf_lo(u1.y) * d1; acc[3] += bf_hi(u1.y) * d1;
            acc[4] += bf_lo(u1.z) * d1; acc[5] += bf_hi(u1.z) * d1;
            acc[6] += bf_lo(u1.w) * d1; acc[7] += bf_hi(u1.w) * d1;
        }
        if (e < end) {
            int s0 = col[e];
            float d0 = dis[s0];
            uint4 u = G[(long)s0 * 16 + seg];
            acc[0] += bf_lo(u.x) * d0; acc[1] += bf_hi(u.x) * d0;
            acc[2] += bf_lo(u.y) * d0; acc[3] += bf_hi(u.y) * d0;
            acc[4] += bf_lo(u.z) * d0; acc[5] += bf_hi(u.z) * d0;
            acc[6] += bf_lo(u.w) * d0; acc[7] += bf_hi(u.w) * d0;
        }
#pragma unroll
        for (int off = 16; off < 64; off <<= 1)
#pragma unroll
            for (int j = 0; j < 8; ++j) acc[j] += __shfl_xor(acc[j], off);

        if (q == 0) {
            const float d = dis[r];
            uint4 u = G[(long)r * 16 + seg];    // self-loop (scaled by dis[r])
            acc[0] += bf_lo(u.x) * d; acc[1] += bf_hi(u.x) * d;
            acc[2] += bf_lo(u.y) * d; acc[3] += bf_hi(u.y) * d;
            acc[4] += bf_lo(u.z) * d; acc[5] += bf_hi(u.z) * d;
            acc[6] += bf_lo(u.w) * d; acc[7] += bf_hi(u.w) * d;
            float o[8];
#pragma unroll
            for (int j = 0; j < 8; ++j) o[j] = fmaxf(acc[j] * d + b1[cl + j], 0.f);
            uint4 pw;
            pw.x = pack2(o[0], o[1]); pw.y = pack2(o[2], o[3]);
            pw.z = pack2(o[4], o[5]); pw.w = pack2(o[6], o[7]);
            *(uint4*)&hs[(w * 4 + rr) * XPAD + cl] = pw;
        }
    }
    __syncthreads();

    // ---- Phase B: hs(16x128) @ W2 -> 16x64; wave w owns cols [w*16, w*16+16) ----
    const int m = lane & 15;
    const ushort_t* arow = &hs[m * XPAD + q * 8];
    const ushort_t* brow = &W2t[(w * 16 + m) * 128 + q * 8];

    f32x4 acc2 = {};
#pragma unroll
    for (int k0 = 0; k0 < 128; k0 += 32) {
        bf16x8 a = *(const bf16x8*)(arow + k0);
        bf16x8 b = *(const bf16x8*)(brow + k0);
        acc2 = __builtin_amdgcn_mfma_f32_16x16x32_bf16(a, b, acc2, 0, 0, 0);
    }

#pragma unroll
    for (int reg = 0; reg < 4; ++reg) {
        int gr = r0 + q * 4 + reg;
        float d = dis[gr];
        g3[(long)gr * OUT_CH + w * 16 + m] = f2bf(acc2[reg] * d);
    }
}

// ===== layer-2 aggregate (bf16 gather, fp32 acc) -> fp32 out =====
// g3 is pre-scaled by dis[src], so plain sum here.

__global__ __launch_bounds__(256) void k_agg2(const int* __restrict__ row_beg,
                                              const int* __restrict__ row_end,
                                              const int* __restrict__ col,
                                              const float* __restrict__ dis,
                                              const ushort_t* __restrict__ g3,
                                              const float* __restrict__ b2,
                                              float* __restrict__ out) {
    int r = blockIdx.x * 4 + (threadIdx.x >> 6);
    if (r >= N_NODES) return;
    const int lane = threadIdx.x & 63;
    const int q = lane >> 3;
    const int seg = lane & 7;
    const int cl = seg << 3;
    const uint4* G = (const uint4*)g3;
    const int beg = row_beg[r], end = row_end[r];

    float acc[8] = {};
    int e = beg + q;
    for (; e + 8 < end; e += 16) {
        int s0 = col[e], s1 = col[e + 8];
        uint4 u0 = G[(long)s0 * 8 + seg];
        uint4 u1 = G[(long)s1 * 8 + seg];
        acc[0] += bf_lo(u0.x); acc[1] += bf_hi(u0.x);
        acc[2] += bf_lo(u0.y); acc[3] += bf_hi(u0.y);
        acc[4] += bf_lo(u0.z); acc[5] += bf_hi(u0.z);
        acc[6] += bf_lo(u0.w); acc[7] += bf_hi(u0.w);
        acc[0] += bf_lo(u1.x); acc[1] += bf_hi(u1.x);
        acc[2] += bf_lo(u1.y); acc[3] += bf_hi(u1.y);
        acc[4] += bf_lo(u1.z); acc[5] += bf_hi(u1.z);
        acc[6] += bf_lo(u1.w); acc[7] += bf_hi(u1.w);
    }
    if (e < end) {
        int s = col[e];
        uint4 u = G[(long)s * 8 + seg];
        acc[0] += bf_lo(u.x); acc[1] += bf_hi(u.x);
        acc[2] += bf_lo(u.y); acc[3] += bf_hi(u.y);
        acc[4] += bf_lo(u.z); acc[5] += bf_hi(u.z);
        acc[6] += bf_lo(u.w); acc[7] += bf_hi(u.w);
    }
#pragma unroll
    for (int off = 8; off < 64; off <<= 1)
#pragma unroll
        for (int j = 0; j < 8; ++j) acc[j] += __shfl_xor(acc[j], off);

    if (q == 0) {
        uint4 u = G[(long)r * 8 + seg];
        acc[0] += bf_lo(u.x); acc[1] += bf_hi(u.x);
        acc[2] += bf_lo(u.y); acc[3] += bf_hi(u.y);
        acc[4] += bf_lo(u.z); acc[5] += bf_hi(u.z);
        acc[6] += bf_lo(u.w); acc[7] += bf_hi(u.w);
        const float d = dis[r];
        float4 o0, o1;
        o0.x = acc[0] * d + b2[cl + 0];
        o0.y = acc[1] * d + b2[cl + 1];
        o0.z = acc[2] * d + b2[cl + 2];
        o0.w = acc[3] * d + b2[cl + 3];
        o1.x = acc[4] * d + b2[cl + 4];
        o1.y = acc[5] * d + b2[cl + 5];
        o1.z = acc[6] * d + b2[cl + 6];
        o1.w = acc[7] * d + b2[cl + 7];
        *(float4*)&out[(long)r * OUT_CH + cl] = o0;
        *(float4*)&out[(long)r * OUT_CH + cl + 4] = o1;
    }
}

// ================= launch =================

extern "C" void kernel_launch(void* const* d_in, const int* in_sizes, int n_in,
                              void* d_out, int out_size, void* d_ws, size_t ws_size,
                              hipStream_t stream) {
    const float* x   = (const float*)d_in[0];
    const int*   ei  = (const int*)d_in[1];
    const float* W1  = (const float*)d_in[2];
    const float* b1  = (const float*)d_in[3];
    const float* W2  = (const float*)d_in[4];
    const float* b2  = (const float*)d_in[5];
    float* out = (float*)d_out;

    const int* src = ei;
    const int* dst = ei + N_EDGES;

    char* p = (char*)d_ws;
    unsigned* rec = (unsigned*)p;         p += (long)NBUCK * BCAP * 4;   // 4.0 MB slack
    int* col     = (int*)p;               p += (long)NBUCK * BCAP * 4;   // 4.0 MB slack
    int* row_beg = (int*)p;               p += 50048 * 4;
    int* row_end = (int*)p;               p += 50048 * 4;
    int* bcur    = (int*)p;               p += 256 * 4;
    float* dis   = (float*)p;             p += 50048 * 4;
    ushort_t* W1t = (ushort_t*)p;         p += 128 * 128 * 2;
    ushort_t* W2t = (ushort_t*)p;         p += 128 * 64 * 2;
    ushort_t* g1  = (ushort_t*)p;         p += (long)N_NODES * HID * 2;
    ushort_t* g3  = (ushort_t*)p;

    k_prep<<<96, 256, 0, stream>>>(W1, W2, W1t, W2t, bcur);
    k_g1<<<(N_NODES + 63) / 64, 256, 0, stream>>>(x, W1t, g1);       // ~12us
    k_sc<<<(N_EDGES + 4095) / 4096, 1024, 0, stream>>>(src, dst, bcur, rec);
    k_csr<<<NBUCK, 1024, 0, stream>>>(bcur, rec, row_beg, row_end, dis, col);
    k_agg1g2<<<3125, 256, 0, stream>>>(row_beg, row_end, col, dis, g1, b1, W2t, g3);
    k_agg2<<<(N_NODES + 3) / 4, 256, 0, stream>>>(row_beg, row_end, col, dis, g3, b2, out);
}